// Round 1
// baseline (864.728 us; speedup 1.0000x reference)
//
#include <hip/hip_runtime.h>

// Problem constants (B=2, S=2048, HIDDEN=1024, HEADS=16, HEAD_DIM=64, ROT=16)
#define S_ 2048
#define EPSF 1e-8f
#define SCALEF 0.125f

typedef short bf16x8 __attribute__((ext_vector_type(8)));
typedef float f32x4 __attribute__((ext_vector_type(4)));

__device__ __forceinline__ unsigned short f2bf(float f){
  unsigned int u = __float_as_uint(f);
  u = (u + 0x7fffu + ((u >> 16) & 1u)) >> 16;
  return (unsigned short)u;
}
__device__ __forceinline__ float bf2f(unsigned short h){
  return __uint_as_float(((unsigned int)h) << 16);
}

// ---------------- 1a: fp32 -> bf16 convert of hidden_states [4096][1024]
__global__ void k_conv_a(const float* __restrict__ A, unsigned short* __restrict__ Ab){
  int i = (blockIdx.x * 256 + threadIdx.x) * 4;   // exact fit: 4096 blocks
  float4 v = *(const float4*)(A + i);
  ushort4 o; o.x=f2bf(v.x); o.y=f2bf(v.y); o.z=f2bf(v.z); o.w=f2bf(v.w);
  *(ushort4*)(Ab + i) = o;
}

// ---------------- 1b: Wqkv cols [0,2048) -> WT bf16 [2048][1024] (transposed)
__global__ void k_conv_wt(const float* __restrict__ W, unsigned short* __restrict__ WT){
  __shared__ float t[32][33];
  int nt = blockIdx.x, kt = blockIdx.y;
  int tx = threadIdx.x & 31, ty = threadIdx.x >> 5;   // 32 x 8
  #pragma unroll
  for (int r = 0; r < 32; r += 8)
    t[ty + r][tx] = W[(size_t)(kt*32 + ty + r)*3072 + nt*32 + tx];
  __syncthreads();
  #pragma unroll
  for (int r = 0; r < 32; r += 8)
    WT[(size_t)(nt*32 + ty + r)*1024 + kt*32 + tx] = f2bf(t[tx][ty + r]);
}

// ---------------- 1c: v0[b,h,d] = hs[b,0,:] @ Wqkv[:, 2048+h*64+d] + bqkv  (exact fp32)
__global__ void k_v0(const float* __restrict__ hs, const float* __restrict__ Wqkv,
                     const float* __restrict__ bqkv, float* __restrict__ v0){
  int bh = blockIdx.x; int b = bh >> 4;
  int d = threadIdx.x;                       // 64 threads
  const float* x = hs + (size_t)b * S_ * 1024;
  int col = 2048 + (bh & 15)*64 + d;
  float acc = bqkv[col];
  for (int k = 0; k < 1024; ++k) acc = fmaf(x[k], Wqkv[(size_t)k*3072 + col], acc);
  v0[bh*64 + d] = acc;
}

// ---------------- 2: QK projection GEMM, M=4096 N=2048 K=1024, bf16 MFMA
// A: Ab [4096][1024] bf16, B: WT [2048][1024] bf16 (n-major). Epilogue: +bias,
// scatter to Q/K [B][H][S][64] bf16.
#define GSTRIDE 72   // LDS row stride in bf16 elems (144B: 16B-aligned, 2-way banks)
__launch_bounds__(256)
__global__ void k_gemm_qk(const unsigned short* __restrict__ Ab,
                          const unsigned short* __restrict__ WT,
                          const float* __restrict__ bqkv,
                          unsigned short* __restrict__ Qb,
                          unsigned short* __restrict__ Kb){
  __shared__ unsigned short At[128*GSTRIDE];
  __shared__ unsigned short Bt[128*GSTRIDE];
  const int m0 = blockIdx.y * 128, n0 = blockIdx.x * 128;
  const int w = threadIdx.x >> 6, l = threadIdx.x & 63;
  const int wr = w >> 1, wc = w & 1;
  f32x4 acc[4][4];
  #pragma unroll
  for (int i = 0; i < 4; ++i)
    #pragma unroll
    for (int j = 0; j < 4; ++j) acc[i][j] = (f32x4){0.f,0.f,0.f,0.f};

  const int srow = threadIdx.x >> 1;          // 0..127
  const int sseg = (threadIdx.x & 1) * 2;     // segs {0,1} or {2,3} of 4x8 elems

  for (int kt = 0; kt < 1024; kt += 32){
    // stage A,B tiles (reg->LDS)
    int4 va0 = *(const int4*)(Ab + (size_t)(m0+srow)*1024 + kt + sseg*8);
    int4 va1 = *(const int4*)(Ab + (size_t)(m0+srow)*1024 + kt + sseg*8 + 8);
    int4 vb0 = *(const int4*)(WT + (size_t)(n0+srow)*1024 + kt + sseg*8);
    int4 vb1 = *(const int4*)(WT + (size_t)(n0+srow)*1024 + kt + sseg*8 + 8);
    *(int4*)&At[srow*GSTRIDE + sseg*8]     = va0;
    *(int4*)&At[srow*GSTRIDE + sseg*8 + 8] = va1;
    *(int4*)&Bt[srow*GSTRIDE + sseg*8]     = vb0;
    *(int4*)&Bt[srow*GSTRIDE + sseg*8 + 8] = vb1;
    __syncthreads();
    bf16x8 af[4], bf[4];
    #pragma unroll
    for (int i = 0; i < 4; ++i)
      af[i] = *(const bf16x8*)&At[(wr*64 + i*16 + (l&15))*GSTRIDE + (l>>4)*8];
    #pragma unroll
    for (int j = 0; j < 4; ++j)
      bf[j] = *(const bf16x8*)&Bt[(wc*64 + j*16 + (l&15))*GSTRIDE + (l>>4)*8];
    #pragma unroll
    for (int i = 0; i < 4; ++i)
      #pragma unroll
      for (int j = 0; j < 4; ++j)
        acc[i][j] = __builtin_amdgcn_mfma_f32_16x16x32_bf16(af[i], bf[j], acc[i][j], 0, 0, 0);
    __syncthreads();
  }
  // epilogue: bias + scatter to Q/K [bh][s][d] bf16
  #pragma unroll
  for (int i = 0; i < 4; ++i){
    #pragma unroll
    for (int j = 0; j < 4; ++j){
      #pragma unroll
      for (int r = 0; r < 4; ++r){
        int m = m0 + wr*64 + i*16 + (l>>4)*4 + r;
        int n = n0 + wc*64 + j*16 + (l&15);
        float v = acc[i][j][r] + bqkv[n];
        int b = m >> 11, s = m & 2047;
        int tsel = n >> 10; int nq = n & 1023;
        int h = nq >> 6, d = nq & 63;
        unsigned short* dst = tsel ? Kb : Qb;
        dst[((size_t)(b*16 + h)*S_ + s)*64 + d] = f2bf(v);
      }
    }
  }
}

// ---------------- 3: RoPE in place on Q,K (first 16 dims per head row)
__global__ void k_rope(unsigned short* __restrict__ Qb, unsigned short* __restrict__ Kb,
                       const int* __restrict__ pos_ids){
  int idx = blockIdx.x * 256 + threadIdx.x;   // 2^20 total: t(1) bh(5) s(11) d(3)
  int d = idx & 7;
  int s = (idx >> 3) & 2047;
  int bh = (idx >> 14) & 31;
  int tsel = idx >> 19;
  unsigned short* X = tsel ? Kb : Qb;
  size_t base = ((size_t)bh * S_ + s) * 64;
  float pos = (float)pos_ids[s];
  float freq = exp2f(-1.6609640474436813f * (float)d);  // 10000^(-d/8)
  float th = pos * freq;
  float sn = sinf(th), cn = cosf(th);
  float x0 = bf2f(X[base + d]), x1 = bf2f(X[base + d + 8]);
  X[base + d]     = f2bf(x0 * cn - x1 * sn);
  X[base + d + 8] = f2bf(x1 * cn + x0 * sn);
}

// ---------------- 4: KA recurrence. One workgroup per (b,h).
// c_0=1 ; c_i = sum_{j<i} e^{s_ij} c_j / (D_i + eps*(D_i + e^{s_ii}))
// Blocked forward substitution, 64-row blocks; scores via MFMA on bf16 Q,K.
#define RSTRIDE 72
__launch_bounds__(256)
__global__ void k_recur(const unsigned short* __restrict__ Qb,
                        const unsigned short* __restrict__ Kb,
                        float* __restrict__ c_g){
  __shared__ unsigned short Qs[64*RSTRIDE];
  __shared__ unsigned short Ks[64*RSTRIDE];
  __shared__ float Es[64*65];
  __shared__ float cs[S_];
  __shared__ float Ps[64], Ds[64];
  const int bh = blockIdx.x;
  const unsigned short* Qh = Qb + (size_t)bh * S_ * 64;
  const unsigned short* Kh = Kb + (size_t)bh * S_ * 64;
  const int w = threadIdx.x >> 6, l = threadIdx.x & 63;
  const int srow = threadIdx.x >> 2;          // 0..63
  const int sseg = (threadIdx.x & 3) * 2;     // segs {0,1},{2,3},{4,5},{6,7}

  for (int bi = 0; bi < 32; ++bi){
    { // stage Q block rows [bi*64, bi*64+64)  (prev iter ended with barrier)
      const unsigned short* src = Qh + (size_t)(bi*64 + srow)*64 + sseg*8;
      int4 v0 = *(const int4*)(src);
      int4 v1 = *(const int4*)(src + 8);
      *(int4*)&Qs[srow*RSTRIDE + sseg*8]     = v0;
      *(int4*)&Qs[srow*RSTRIDE + sseg*8 + 8] = v1;
    }
    float Pr[4] = {0.f,0.f,0.f,0.f}, Dr[4] = {0.f,0.f,0.f,0.f};
    for (int bj = 0; bj <= bi; ++bj){
      __syncthreads();   // Q staged visible; prev Ks reads done
      { // stage K block bj
        const unsigned short* src = Kh + (size_t)(bj*64 + srow)*64 + sseg*8;
        int4 v0 = *(const int4*)(src);
        int4 v1 = *(const int4*)(src + 8);
        *(int4*)&Ks[srow*RSTRIDE + sseg*8]     = v0;
        *(int4*)&Ks[srow*RSTRIDE + sseg*8 + 8] = v1;
      }
      __syncthreads();
      // S block: wave w -> rows [w*16, w*16+16), cols 0..63
      f32x4 acc[4];
      #pragma unroll
      for (int t = 0; t < 4; ++t) acc[t] = (f32x4){0.f,0.f,0.f,0.f};
      #pragma unroll
      for (int ks = 0; ks < 2; ++ks){
        bf16x8 a = *(const bf16x8*)&Qs[(w*16 + (l&15))*RSTRIDE + ks*32 + (l>>4)*8];
        #pragma unroll
        for (int t = 0; t < 4; ++t){
          bf16x8 b = *(const bf16x8*)&Ks[(t*16 + (l&15))*RSTRIDE + ks*32 + (l>>4)*8];
          acc[t] = __builtin_amdgcn_mfma_f32_16x16x32_bf16(a, b, acc[t], 0, 0, 0);
        }
      }
      if (bj < bi){
        float cv[4];
        #pragma unroll
        for (int t = 0; t < 4; ++t) cv[t] = cs[bj*64 + t*16 + (l&15)];
        #pragma unroll
        for (int r = 0; r < 4; ++r){
          float ps = 0.f, ds = 0.f;
          #pragma unroll
          for (int t = 0; t < 4; ++t){
            float e = __expf(acc[t][r] * SCALEF);
            ps = fmaf(e, cv[t], ps); ds += e;
          }
          #pragma unroll
          for (int mm = 1; mm < 16; mm <<= 1){
            ps += __shfl_xor(ps, mm); ds += __shfl_xor(ds, mm);
          }
          Pr[r] += ps; Dr[r] += ds;
        }
      } else {
        // diagonal block: E -> LDS (padded), P/D -> LDS
        #pragma unroll
        for (int r = 0; r < 4; ++r){
          int row = w*16 + (l>>4)*4 + r;
          #pragma unroll
          for (int t = 0; t < 4; ++t)
            Es[row*65 + t*16 + (l&15)] = __expf(acc[t][r] * SCALEF);
        }
        if ((l & 15) == 0){
          #pragma unroll
          for (int r = 0; r < 4; ++r){
            int row = w*16 + (l>>4)*4 + r;
            Ps[row] = Pr[r]; Ds[row] = Dr[r];
          }
        }
      }
    }
    __syncthreads();
    // serial solve (wave 0): broadcast-update, prefetched E column
    if (w == 0){
      const int rr = l;
      float Pl = Ps[rr], Dl = Ds[rr];
      float dE = Es[rr*65 + rr];
      float cval = 0.f;
      float e0 = Es[rr*65 + 0];
      for (int r = 0; r < 64; ++r){
        float e1 = Es[rr*65 + r + 1];          // prefetch (pad covers r=63)
        float Pb = __shfl(Pl, r), Db = __shfl(Dl, r), Eb = __shfl(dE, r);
        float cr;
        if (bi == 0 && r == 0) cr = 1.0f;
        else cr = Pb / (Db + EPSF * (Db + Eb));
        if (rr == r) cval = cr;
        if (rr > r){ Pl = fmaf(e0, cr, Pl); Dl += e0; }
        e0 = e1;
      }
      cs[bi*64 + rr] = cval;
      c_g[((size_t)(bh >> 4) * S_ + (bi*64 + rr)) * 16 + (bh & 15)] = cval;
    }
    __syncthreads();
  }
}

// ---------------- 5a: U[b,h,n] = sum_d v0[b,h,d] * Wd[h*64+d][n]
__global__ void k_u(const float* __restrict__ v0, const float* __restrict__ Wd,
                    float* __restrict__ U){
  int bh = blockIdx.x; int h = bh & 15;
  __shared__ float vsh[64];
  if (threadIdx.x < 64) vsh[threadIdx.x] = v0[bh*64 + threadIdx.x];
  __syncthreads();
  for (int n = threadIdx.x; n < 1024; n += 256){
    float acc = 0.f;
    #pragma unroll 8
    for (int d = 0; d < 64; ++d) acc = fmaf(vsh[d], Wd[(size_t)(h*64 + d)*1024 + n], acc);
    U[(size_t)bh*1024 + n] = acc;
  }
}

// ---------------- 5b: out[b,s,n] = bd[n] + sum_h c[b,s,h] * U[b,h,n]
__global__ void k_out(const float* __restrict__ c_g, const float* __restrict__ U,
                      const float* __restrict__ bd, float* __restrict__ out){
  int bs = blockIdx.x; int b = bs >> 11;
  __shared__ float ch[16];
  if (threadIdx.x < 16) ch[threadIdx.x] = c_g[(size_t)bs*16 + threadIdx.x];
  __syncthreads();
  int n = threadIdx.x * 4;
  float4 acc = *(const float4*)(bd + n);
  #pragma unroll
  for (int h = 0; h < 16; ++h){
    float cc = ch[h];
    float4 u = *(const float4*)(U + ((size_t)(b*16 + h))*1024 + n);
    acc.x = fmaf(cc, u.x, acc.x); acc.y = fmaf(cc, u.y, acc.y);
    acc.z = fmaf(cc, u.z, acc.z); acc.w = fmaf(cc, u.w, acc.w);
  }
  *(float4*)(out + (size_t)bs*1024 + n) = acc;
}

extern "C" void kernel_launch(void* const* d_in, const int* in_sizes, int n_in,
                              void* d_out, int out_size, void* d_ws, size_t ws_size,
                              hipStream_t stream) {
  const float* hs   = (const float*)d_in[0];   // [2][2048][1024]
  const int*   pos  = (const int*)d_in[1];     // [2048]
  const float* Wqkv = (const float*)d_in[2];   // [1024][3072]
  const float* bqkv = (const float*)d_in[3];   // [3072]
  const float* Wd   = (const float*)d_in[4];   // [1024][1024]
  const float* bd   = (const float*)d_in[5];   // [1024]
  float* out = (float*)d_out;

  // workspace layout (~28.5 MB total)
  char* ws = (char*)d_ws;
  unsigned short* Ab = (unsigned short*)(ws);                       // 8 MB
  unsigned short* WT = (unsigned short*)(ws + (8u<<20));            // 4 MB
  unsigned short* Qb = (unsigned short*)(ws + (12u<<20));           // 8 MB
  unsigned short* Kb = (unsigned short*)(ws + (20u<<20));           // 8 MB
  float* v0  = (float*)(ws + (28u<<20));                            // 8 KB
  float* c_g = (float*)(ws + (28u<<20) + (1u<<16));                 // 256 KB
  float* U   = (float*)(ws + (28u<<20) + (1u<<16) + (1u<<18));      // 128 KB

  k_conv_a <<<4096, 256, 0, stream>>>(hs, Ab);
  k_conv_wt<<<dim3(64, 32), 256, 0, stream>>>(Wqkv, WT);
  k_v0     <<<32, 64, 0, stream>>>(hs, Wqkv, bqkv, v0);
  k_gemm_qk<<<dim3(16, 32), 256, 0, stream>>>(Ab, WT, bqkv, Qb, Kb);
  k_rope   <<<4096, 256, 0, stream>>>(Qb, Kb, pos);
  k_recur  <<<32, 256, 0, stream>>>(Qb, Kb, c_g);
  k_u      <<<32, 256, 0, stream>>>(v0, Wd, U);
  k_out    <<<4096, 256, 0, stream>>>(c_g, U, bd, out);
}